// Round 15
// baseline (78013.885 us; speedup 1.0000x reference)
//
#include <hip/hip_runtime.h>

#define T_STEPS 32768
#define THREADS 256
#define NLAUNCH 256   // 1 block per CU (register-forced exclusivity); 64 become workers
#define D_SLOTS 8     // h rotation depth (skew <= 1; window for projection lag)

typedef unsigned int uint32;
typedef unsigned long long ull;
typedef unsigned int u32x4 __attribute__((ext_vector_type(4)));
typedef unsigned int u32x2 __attribute__((ext_vector_type(2)));

// ws layout:
// [0, 65536)        : hrot = ull[2 lstm][8 slots][512]; each ull = {lo: tag=t+1, hi: f32 h}
// [65536, 73728)    : ready = u32[2 lstm][8 slots][128]  (per-producer-wave flags)
// [73728, 73856)    : claim area (32 uints)

__device__ inline float fsig(float x) {
    return __builtin_amdgcn_rcpf(1.f + __expf(-x));
}
__device__ inline float ftanh(float x) {
    return 1.f - 2.f * __builtin_amdgcn_rcpf(1.f + __expf(2.f * x));
}
__device__ inline float wred64(float x) {
    x += __shfl_xor(x, 1);  x += __shfl_xor(x, 2);  x += __shfl_xor(x, 4);
    x += __shfl_xor(x, 8);  x += __shfl_xor(x, 16); x += __shfl_xor(x, 32);
    return x;
}

// Consumer loads: nt+sc0 = no-allocate in L1 -> served by the XCD-local L2
// that producers write through to (R10-14 proven fresh; FETCH stays ~15MB).
__device__ inline void pollflag(const uint32* p, u32x2& f) {
    asm volatile("global_load_dwordx2 %0, %1, off sc0 nt\n\t"
                 "s_waitcnt vmcnt(0)"
                 : "=v"(f) : "v"(p) : "memory");
}
__device__ inline void poll4x(const ull* p, u32x4& v0, u32x4& v1, u32x4& v2, u32x4& v3) {
    asm volatile("global_load_dwordx4 %0, %4, off sc0 nt\n\t"
                 "global_load_dwordx4 %1, %4, off offset:1024 sc0 nt\n\t"
                 "global_load_dwordx4 %2, %4, off offset:2048 sc0 nt\n\t"
                 "global_load_dwordx4 %3, %4, off offset:3072 sc0 nt\n\t"
                 "s_waitcnt vmcnt(0)"
                 : "=&v"(v0), "=&v"(v1), "=&v"(v2), "=&v"(v3)
                 : "v"(p) : "memory");
}

// claim-phase primitives (agent scope; startup-only)
__device__ inline uint32 a_add(uint32* p, uint32 v) {
    return __hip_atomic_fetch_add(p, v, __ATOMIC_RELAXED, __HIP_MEMORY_SCOPE_AGENT);
}
__device__ inline uint32 a_ld(const uint32* p) {
    return __hip_atomic_load(p, __ATOMIC_RELAXED, __HIP_MEMORY_SCOPE_AGENT);
}
__device__ inline void a_st(uint32* p, uint32 v) {
    __hip_atomic_store(p, v, __ATOMIC_RELAXED, __HIP_MEMORY_SCOPE_AGENT);
}

__global__ __launch_bounds__(THREADS, 1)
void lstm_persistent(const float* __restrict__ sa,
                     const float* __restrict__ W_ih1, const float* __restrict__ W_hh1,
                     const float* __restrict__ b_ih1, const float* __restrict__ b_hh1,
                     const float* __restrict__ W_ih2, const float* __restrict__ W_hh2,
                     const float* __restrict__ b_ih2, const float* __restrict__ b_hh2,
                     const float* __restrict__ W_xyz, const float* __restrict__ b_xyz,
                     const float* __restrict__ W_zeta, const float* __restrict__ b_zeta,
                     const float* __restrict__ W_uvw, const float* __restrict__ b_uvw,
                     const float* __restrict__ W_pqr, const float* __restrict__ b_pqr,
                     float* __restrict__ out, ull* hrot, uint32* ready, uint32* claim)
{
    const int tid  = threadIdx.x;
    const int wv   = tid >> 6;    // wave 0..3
    const int lane = tid & 63;

    __shared__ int s_lstm, s_w;

    // ---- per-XCD role claiming: one LSTM per XCD (thread 0; R11-14 proven) ----
    if (tid == 0) {
        uint32 xcc;
        asm volatile("s_getreg_b32 %0, hwreg(HW_REG_XCC_ID)" : "=s"(xcc));
        xcc &= 7;
        uint32* cnt     = claim;
        uint32* rankcnt = claim + 8;
        uint32* grank   = claim + 16;

        int lstm = -1, w = 0;
        uint32 slot = a_add(&cnt[xcc], 1);
        if (slot < 32) {
            w = (int)slot;
            if (slot == 31) {
                uint32 rank = a_add(rankcnt, 1);
                a_st(&grank[xcc], (rank < 2) ? (rank + 1) : 0xFEu);
            }
            uint32 g;
            long spins = 0;
            for (;;) {
                g = a_ld(&grank[xcc]);
                if (g != 0) break;
                if (a_ld(rankcnt) >= 2 && ++spins > 200000) { g = 0xFEu; break; }
            }
            if (g != 0xFEu) lstm = (int)g - 1;
        }
        s_lstm = lstm; s_w = w;
    }
    __syncthreads();
    const int lstm = s_lstm;
    const int w    = s_w;
    if (lstm < 0) return;

    const float* W_ih = lstm ? W_ih2 : W_ih1;
    const float* W_hh = lstm ? W_hh2 : W_hh1;
    const float* b_ih = lstm ? b_ih2 : b_ih1;
    const float* b_hh = lstm ? b_hh2 : b_hh1;
    const float* W_a  = lstm ? W_zeta : W_xyz;
    const float* W_b  = lstm ? W_pqr  : W_uvw;

    ull*    hb  = hrot  + (size_t)lstm * D_SLOTS * 512;
    uint32* rdy = ready + lstm * (D_SLOTS * 128);

    // wave-private h copies (528 = 4*132 padded); shared read-only tables
    __shared__ __align__(16) float hw_all[4][528];
    __shared__ float wih_lds[64 * 19];
    __shared__ float pj_lds[6 * 512];
    float* hw = hw_all[wv];

    // lane decomposition: row r = lane>>2 (16 rows/wave), col-block cb = lane&3
    const int r  = lane >> 2;
    const int cb = lane & 3;
    const int gt = r >> 2;        // gate 0..3 (i,f,g,o)
    const int jj = r & 3;         // j within wave's 4
    const int G  = gt * 512 + (w << 4) + (wv << 2) + jj;   // global gate row

    // W_hh slice: 128 weights / thread in AGPRs (R8+ proven resident)
    float wa[128];
    {
        const float4* wp4 = (const float4*)(W_hh + (size_t)G * 512 + cb * 128);
        #pragma unroll
        for (int k = 0; k < 32; ++k) {
            float4 t4 = wp4[k];
            asm volatile("v_accvgpr_write_b32 %0, %1" : "=a"(wa[4 * k + 0]) : "v"(t4.x));
            asm volatile("v_accvgpr_write_b32 %0, %1" : "=a"(wa[4 * k + 1]) : "v"(t4.y));
            asm volatile("v_accvgpr_write_b32 %0, %1" : "=a"(wa[4 * k + 2]) : "v"(t4.z));
            asm volatile("v_accvgpr_write_b32 %0, %1" : "=a"(wa[4 * k + 3]) : "v"(t4.w));
        }
    }
    // W_ih rows (layout: [wv*16 + r][19])
    for (int idx = tid; idx < 64 * 19; idx += THREADS) {
        int rr = idx / 19, kk = idx - rr * 19;
        int v2 = rr >> 4, r2 = rr & 15;
        int G2 = (r2 >> 2) * 512 + (w << 4) + (v2 << 2) + (r2 & 3);
        wih_lds[idx] = W_ih[G2 * 19 + kk];
    }
    // full projection weights
    for (int idx = tid; idx < 6 * 512; idx += THREADS) {
        int o = idx >> 9, c = idx & 511;
        pj_lds[idx] = (o < 3) ? W_a[o * 512 + c] : W_b[(o - 3) * 512 + c];
    }
    const float bsum = b_ih[G] + b_hh[G];

    // AGPR ballast: keep total regs/wave high -> 1 wave/SIMD -> CU-exclusive WG
    float ball[16];
    #pragma unroll
    for (int k = 0; k < 16; ++k)
        asm volatile("v_accvgpr_write_b32 %0, %1" : "=a"(ball[k]) : "v"(bsum));

    // projection biases: wave wv in {1,2,3} owns dots d0=2(wv-1), d0+1
    const int d0 = 2 * (wv - 1);
    float pb0 = 0.f, pb1 = 0.f;
    int   col0 = 0, col1 = 0;
    if (wv >= 1) {
        const float* ba = lstm ? b_zeta : b_xyz;
        const float* bb = lstm ? b_pqr  : b_uvw;
        pb0  = (d0 < 3)     ? ba[d0]     : bb[d0 - 3];
        pb1  = (d0 + 1 < 3) ? ba[d0 + 1] : bb[d0 - 2];
        col0 = (d0 < 3)     ? 3 * lstm + d0       : 6 + 3 * lstm + (d0 - 3);
        col1 = (d0 + 1 < 3) ? 3 * lstm + (d0 + 1) : 6 + 3 * lstm + (d0 - 2);
    }

    float c_reg = 0.0f;
    __syncthreads();   // tables ready; loop below is barrier-free

    float sav = (lane < 19) ? sa[lane] : 0.f;

    for (int t = 0; t <= T_STEPS; ++t) {
        // final iteration: only waves 1-3 of the WG that projects out[T-1]
        if (t == T_STEPS && !(wv >= 1 && ((t - 1) & 31) == w)) break;

        // ---- 0. gx from sav (pre-poll, off the post-detect path) ----
        float gxv = bsum;
        if (t < T_STEPS) {
            const int base = (wv * 16 + r) * 19;
            #pragma unroll
            for (int k = 0; k < 19; ++k)
                gxv = fmaf(__shfl(sav, k), wih_lds[base + k], gxv);
        }
        float sav_n = 0.f;
        if (lane < 19 && t + 1 < T_STEPS) sav_n = sa[(size_t)(t + 1) * 19 + lane];

        // ---- 1. flag spin (512B footprint) + one bulk data gather ----
        if (t > 0) {
            const uint32 tag  = (uint32)t;
            const int    slot = (int)((uint32)(t - 1) & (D_SLOTS - 1));
            const uint32* fp  = rdy + slot * 128 + 2 * lane;
            u32x2 f;
            for (;;) {
                pollflag(fp, f);
                if (__all((f.x == tag) && (f.y == tag))) break;
            }
            // data now durable in L2 (producers vmcnt-ack'd before flag)
            ull* sp = hb + (size_t)slot * 512 + 2 * lane;
            u32x4 v0, v1, v2, v3;
            for (;;) {                       // expected single iteration
                poll4x(sp, v0, v1, v2, v3);
                if (v0.x == tag && v0.z == tag && v1.x == tag && v1.z == tag &&
                    v2.x == tag && v2.z == tag && v3.x == tag && v3.z == tag) break;
            }
            *(float2*)&hw[      2 * lane] = make_float2(__uint_as_float(v0.y), __uint_as_float(v0.w));
            *(float2*)&hw[132 + 2 * lane] = make_float2(__uint_as_float(v1.y), __uint_as_float(v1.w));
            *(float2*)&hw[264 + 2 * lane] = make_float2(__uint_as_float(v2.y), __uint_as_float(v2.w));
            *(float2*)&hw[396 + 2 * lane] = make_float2(__uint_as_float(v3.y), __uint_as_float(v3.w));
        } else if (t == 0) {
            *(float2*)&hw[      2 * lane] = make_float2(0.f, 0.f);
            *(float2*)&hw[132 + 2 * lane] = make_float2(0.f, 0.f);
            *(float2*)&hw[264 + 2 * lane] = make_float2(0.f, 0.f);
            *(float2*)&hw[396 + 2 * lane] = make_float2(0.f, 0.f);
        }

        if (t < T_STEPS) {
            // ---- 2. mat-vec: row r, cols [cb*128, +128) ----
            float part = (cb == 0) ? gxv : 0.f;
            {
                const float4* hp4 = (const float4*)&hw[cb * 132];
                float ax = 0.f, ay = 0.f, az = 0.f, aw2 = 0.f;
                #pragma unroll
                for (int k = 0; k < 32; ++k) {
                    float4 hv = hp4[k];
                    float w0, w1, w2, w3;
                    asm volatile("v_accvgpr_read_b32 %0, %1" : "=v"(w0) : "a"(wa[4 * k + 0]));
                    asm volatile("v_accvgpr_read_b32 %0, %1" : "=v"(w1) : "a"(wa[4 * k + 1]));
                    asm volatile("v_accvgpr_read_b32 %0, %1" : "=v"(w2) : "a"(wa[4 * k + 2]));
                    asm volatile("v_accvgpr_read_b32 %0, %1" : "=v"(w3) : "a"(wa[4 * k + 3]));
                    ax  = fmaf(w0, hv.x, ax);
                    ay  = fmaf(w1, hv.y, ay);
                    az  = fmaf(w2, hv.z, az);
                    aw2 = fmaf(w3, hv.w, aw2);
                }
                part += (ax + ay) + (az + aw2);
            }
            part += __shfl_xor(part, 1);
            part += __shfl_xor(part, 2);

            // ---- 3. gates + cell update ----
            float act = (gt == 2) ? ftanh(part) : fsig(part);
            float i_v = __shfl(act, 4 * jj);
            float f_v = __shfl(act, 16 + 4 * jj);
            float g_v = __shfl(act, 32 + 4 * jj);
            float o_v = __shfl(act, 48 + 4 * jj);

            float hn = 0.f;
            if (r < 4 && cb == 0) {      // lanes 0,4,8,12 own rows j=0..3
                c_reg = f_v * c_reg + i_v * g_v;
                hn    = o_v * ftanh(c_reg);
            }
            // ---- 4. publish: lane 0 stores the wave's 4 fused words into the
            //      local XCD L2 (write-through, NO nt), acks, then releases flag ----
            {
                const uint32 tag2 = (uint32)(t + 1);
                float h1 = __shfl(hn, 4), h2 = __shfl(hn, 8), h3 = __shfl(hn, 12);
                const int slot_t = (int)((uint32)t & (D_SLOTS - 1));
                if (lane == 0) {
                    ull* p = hb + (size_t)slot_t * 512 + (w << 4) + (wv << 2);
                    u32x4 A, B;
                    A.x = tag2; A.y = __float_as_uint(hn);
                    A.z = tag2; A.w = __float_as_uint(h1);
                    B.x = tag2; B.y = __float_as_uint(h2);
                    B.z = tag2; B.w = __float_as_uint(h3);
                    asm volatile("global_store_dwordx4 %0, %1, off sc0\n\t"
                                 "global_store_dwordx4 %2, %3, off sc0"
                                 :: "v"(p), "v"(A), "v"(p + 2), "v"(B) : "memory");
                    asm volatile("s_waitcnt vmcnt(0)" ::: "memory");   // L2-ack (fast)
                    uint32* fq = rdy + slot_t * 128 + (w << 2) + wv;
                    asm volatile("global_store_dword %0, %1, off sc0"
                                 :: "v"(fq), "v"(tag2) : "memory");    // release flag
                }
            }
        }

        // ---- 5. projection of h_{t-1} (waves 1-3 split 2 dots each; after publish) ----
        if (t > 0 && wv >= 1 && ((t - 1) & 31) == w) {
            float a0 = 0.f, a1 = 0.f;
            #pragma unroll
            for (int m = 0; m < 8; ++m) {
                int c = lane + (m << 6);
                float hv = hw[((c >> 7) * 132) + (c & 127)];
                a0 = fmaf(hv, pj_lds[d0 * 512 + c],       a0);
                a1 = fmaf(hv, pj_lds[(d0 + 1) * 512 + c], a1);
            }
            a0 = wred64(a0); a1 = wred64(a1);
            if (lane == 0) {
                size_t ob = (size_t)(t - 1) * 12;
                out[ob + col0] = a0 + pb0;
                out[ob + col1] = a1 + pb1;
            }
        }
        sav = sav_n;
    }

    // keep ballast AGPRs live (branch never taken; compiler can't prove it)
    if (lstm < -1) {
        float s = 0.f;
        #pragma unroll
        for (int k = 0; k < 16; ++k) {
            float tv;
            asm volatile("v_accvgpr_read_b32 %0, %1" : "=v"(tv) : "a"(ball[k]));
            s += tv;
        }
        ((float*)claim)[31] = s;
    }
}

extern "C" void kernel_launch(void* const* d_in, const int* in_sizes, int n_in,
                              void* d_out, int out_size, void* d_ws, size_t ws_size,
                              hipStream_t stream)
{
    const float* sa    = (const float*)d_in[0];
    const float* W_ih1 = (const float*)d_in[1];
    const float* W_hh1 = (const float*)d_in[2];
    const float* b_ih1 = (const float*)d_in[3];
    const float* b_hh1 = (const float*)d_in[4];
    const float* W_ih2 = (const float*)d_in[5];
    const float* W_hh2 = (const float*)d_in[6];
    const float* b_ih2 = (const float*)d_in[7];
    const float* b_hh2 = (const float*)d_in[8];
    const float* W_xyz = (const float*)d_in[9];
    const float* b_xyz = (const float*)d_in[10];
    const float* W_zeta= (const float*)d_in[11];
    const float* b_zeta= (const float*)d_in[12];
    const float* W_uvw = (const float*)d_in[13];
    const float* b_uvw = (const float*)d_in[14];
    const float* W_pqr = (const float*)d_in[15];
    const float* b_pqr = (const float*)d_in[16];

    float*  out   = (float*)d_out;
    ull*    hrot  = (ull*)d_ws;
    uint32* ready = (uint32*)((char*)d_ws + 65536);
    uint32* claim = (uint32*)((char*)d_ws + 65536 + 8192);

    // zero hrot tags + ready flags + claim area every call (graph-replayed)
    hipMemsetAsync(d_ws, 0, 65536 + 8192 + 128, stream);

    lstm_persistent<<<NLAUNCH, THREADS, 0, stream>>>(
        sa, W_ih1, W_hh1, b_ih1, b_hh1, W_ih2, W_hh2, b_ih2, b_hh2,
        W_xyz, b_xyz, W_zeta, b_zeta, W_uvw, b_uvw, W_pqr, b_pqr,
        out, hrot, ready, claim);
}

// Round 16
// 77025.159 us; speedup vs baseline: 1.0128x; 1.0128x over previous
//
#include <hip/hip_runtime.h>

#define T_STEPS 32768
#define THREADS 256
#define NLAUNCH 256   // 1 block per CU (register-forced exclusivity); 64 become workers
#define D_SLOTS 8     // h rotation depth

typedef unsigned int uint32;
typedef unsigned long long ull;
typedef unsigned int u32x4 __attribute__((ext_vector_type(4)));

// ws layout:
// [0, 65536)     : hrot = ull[2 lstm][8 slots][512]; each ull = {lo: tag=t+1, hi: f32 h}
// [65536, 65664) : claim area (32 uints)

__device__ inline float fsig(float x) {
    return __builtin_amdgcn_rcpf(1.f + __expf(-x));
}
__device__ inline float ftanh(float x) {
    return 1.f - 2.f * __builtin_amdgcn_rcpf(1.f + __expf(2.f * x));
}
__device__ inline float wred64(float x) {
    x += __shfl_xor(x, 1);  x += __shfl_xor(x, 2);  x += __shfl_xor(x, 4);
    x += __shfl_xor(x, 8);  x += __shfl_xor(x, 16); x += __shfl_xor(x, 32);
    return x;
}

// Issue one 4-load generation (no wait): nt+sc0 = L1 no-allocate -> served by
// the XCD-local L2 the producers write through to (R10-15 proven fresh).
#define POLL_ISSUE(sp, v0, v1, v2, v3)                                       \
    asm volatile("global_load_dwordx4 %0, %4, off sc0 nt\n\t"                \
                 "global_load_dwordx4 %1, %4, off offset:1024 sc0 nt\n\t"    \
                 "global_load_dwordx4 %2, %4, off offset:2048 sc0 nt\n\t"    \
                 "global_load_dwordx4 %3, %4, off offset:3072 sc0 nt"        \
                 : "=&v"(v0), "=&v"(v1), "=&v"(v2), "=&v"(v3)                \
                 : "v"(sp) : "memory")

#define WAIT4()                                                              \
    do { asm volatile("s_waitcnt vmcnt(4)" ::: "memory");                    \
         __builtin_amdgcn_sched_barrier(0); } while (0)

// claim-phase primitives (agent scope; startup-only) + memory-side rescue RMW
__device__ inline uint32 a_add(uint32* p, uint32 v) {
    return __hip_atomic_fetch_add(p, v, __ATOMIC_RELAXED, __HIP_MEMORY_SCOPE_AGENT);
}
__device__ inline uint32 a_ld(const uint32* p) {
    return __hip_atomic_load(p, __ATOMIC_RELAXED, __HIP_MEMORY_SCOPE_AGENT);
}
__device__ inline void a_st(uint32* p, uint32 v) {
    __hip_atomic_store(p, v, __ATOMIC_RELAXED, __HIP_MEMORY_SCOPE_AGENT);
}
__device__ inline ull rescue_rmw(ull* p) {
    return __hip_atomic_fetch_add(p, 0ull, __ATOMIC_RELAXED, __HIP_MEMORY_SCOPE_AGENT);
}

__global__ __launch_bounds__(THREADS, 1)
void lstm_persistent(const float* __restrict__ sa,
                     const float* __restrict__ W_ih1, const float* __restrict__ W_hh1,
                     const float* __restrict__ b_ih1, const float* __restrict__ b_hh1,
                     const float* __restrict__ W_ih2, const float* __restrict__ W_hh2,
                     const float* __restrict__ b_ih2, const float* __restrict__ b_hh2,
                     const float* __restrict__ W_xyz, const float* __restrict__ b_xyz,
                     const float* __restrict__ W_zeta, const float* __restrict__ b_zeta,
                     const float* __restrict__ W_uvw, const float* __restrict__ b_uvw,
                     const float* __restrict__ W_pqr, const float* __restrict__ b_pqr,
                     float* __restrict__ out, ull* hrot, uint32* claim)
{
    const int tid  = threadIdx.x;
    const int wv   = tid >> 6;    // wave 0..3
    const int lane = tid & 63;

    __shared__ int s_lstm, s_w;

    // ---- per-XCD role claiming: one LSTM per XCD (thread 0; R11-15 proven) ----
    if (tid == 0) {
        uint32 xcc;
        asm volatile("s_getreg_b32 %0, hwreg(HW_REG_XCC_ID)" : "=s"(xcc));
        xcc &= 7;
        uint32* cnt     = claim;
        uint32* rankcnt = claim + 8;
        uint32* grank   = claim + 16;

        int lstm = -1, w = 0;
        uint32 slot = a_add(&cnt[xcc], 1);
        if (slot < 32) {
            w = (int)slot;
            if (slot == 31) {
                uint32 rank = a_add(rankcnt, 1);
                a_st(&grank[xcc], (rank < 2) ? (rank + 1) : 0xFEu);
            }
            uint32 g;
            long spins = 0;
            for (;;) {
                g = a_ld(&grank[xcc]);
                if (g != 0) break;
                if (a_ld(rankcnt) >= 2 && ++spins > 200000) { g = 0xFEu; break; }
            }
            if (g != 0xFEu) lstm = (int)g - 1;
        }
        s_lstm = lstm; s_w = w;
    }
    __syncthreads();
    const int lstm = s_lstm;
    const int w    = s_w;
    if (lstm < 0) return;

    const float* W_ih = lstm ? W_ih2 : W_ih1;
    const float* W_hh = lstm ? W_hh2 : W_hh1;
    const float* b_ih = lstm ? b_ih2 : b_ih1;
    const float* b_hh = lstm ? b_hh2 : b_hh1;
    const float* W_a  = lstm ? W_zeta : W_xyz;
    const float* W_b  = lstm ? W_pqr  : W_uvw;

    ull* hb = hrot + (size_t)lstm * D_SLOTS * 512;

    // wave-private h copies (528 = 4*132 padded); shared read-only tables
    __shared__ __align__(16) float hw_all[4][528];
    __shared__ float wih_lds[64 * 19];
    __shared__ float pj_lds[6 * 512];
    float* hw = hw_all[wv];

    // lane decomposition: row r = lane>>2 (16 rows/wave), col-block cb = lane&3
    const int r  = lane >> 2;
    const int cb = lane & 3;
    const int gt = r >> 2;        // gate 0..3 (i,f,g,o)
    const int jj = r & 3;         // j within wave's 4
    const int G  = gt * 512 + (w << 4) + (wv << 2) + jj;   // global gate row

    // W_hh slice: 128 weights / thread in AGPRs (R8+ proven resident)
    float wa[128];
    {
        const float4* wp4 = (const float4*)(W_hh + (size_t)G * 512 + cb * 128);
        #pragma unroll
        for (int k = 0; k < 32; ++k) {
            float4 t4 = wp4[k];
            asm volatile("v_accvgpr_write_b32 %0, %1" : "=a"(wa[4 * k + 0]) : "v"(t4.x));
            asm volatile("v_accvgpr_write_b32 %0, %1" : "=a"(wa[4 * k + 1]) : "v"(t4.y));
            asm volatile("v_accvgpr_write_b32 %0, %1" : "=a"(wa[4 * k + 2]) : "v"(t4.z));
            asm volatile("v_accvgpr_write_b32 %0, %1" : "=a"(wa[4 * k + 3]) : "v"(t4.w));
        }
    }
    // W_ih rows (layout: [wv*16 + r][19])
    for (int idx = tid; idx < 64 * 19; idx += THREADS) {
        int rr = idx / 19, kk = idx - rr * 19;
        int v2 = rr >> 4, r2 = rr & 15;
        int G2 = (r2 >> 2) * 512 + (w << 4) + (v2 << 2) + (r2 & 3);
        wih_lds[idx] = W_ih[G2 * 19 + kk];
    }
    // full projection weights
    for (int idx = tid; idx < 6 * 512; idx += THREADS) {
        int o = idx >> 9, c = idx & 511;
        pj_lds[idx] = (o < 3) ? W_a[o * 512 + c] : W_b[(o - 3) * 512 + c];
    }
    const float bsum = b_ih[G] + b_hh[G];

    // AGPR ballast: keep total regs/wave > 256 -> 1 wave/SIMD -> CU-exclusive
    float ball[16];
    #pragma unroll
    for (int k = 0; k < 16; ++k)
        asm volatile("v_accvgpr_write_b32 %0, %1" : "=a"(ball[k]) : "v"(bsum));

    // projection: wave wv in {1,2,3} owns dots d0=2(wv-1), d0+1
    const int d0 = 2 * (wv - 1);
    float pb0 = 0.f, pb1 = 0.f;
    int   col0 = 0, col1 = 0;
    if (wv >= 1) {
        const float* ba = lstm ? b_zeta : b_xyz;
        const float* bb = lstm ? b_pqr  : b_uvw;
        pb0  = (d0 < 3)     ? ba[d0]     : bb[d0 - 3];
        pb1  = (d0 + 1 < 3) ? ba[d0 + 1] : bb[d0 - 2];
        col0 = (d0 < 3)     ? 3 * lstm + d0       : 6 + 3 * lstm + (d0 - 3);
        col1 = (d0 + 1 < 3) ? 3 * lstm + (d0 + 1) : 6 + 3 * lstm + (d0 - 2);
    }

    float c_reg = 0.0f;
    __syncthreads();   // tables ready; loop below is barrier-free

    float sav = (lane < 19) ? sa[lane] : 0.f;

    for (int t = 0; t <= T_STEPS; ++t) {
        // final iteration: only waves 1-3 of the WG that projects out[T-1]
        if (t == T_STEPS && !(wv >= 1 && ((t - 1) & 31) == w)) break;

        // ---- 0. gx from sav (pre-poll; fills wait time) ----
        float gxv = bsum;
        if (t < T_STEPS) {
            const int base = (wv * 16 + r) * 19;
            #pragma unroll
            for (int k = 0; k < 19; ++k)
                gxv = fmaf(__shfl(sav, k), wih_lds[base + k], gxv);
        }
        float sav_n = 0.f;
        if (lane < 19 && t + 1 < T_STEPS) sav_n = sa[(size_t)(t + 1) * 19 + lane];

        // ---- 1. pipelined single-trip poll + incremental chunk retirement ----
        if (t > 0) {
            ull* sp = hb + (size_t)((uint32)(t - 1) & (D_SLOTS - 1)) * 512 + 2 * lane;
            const uint32 tag = (uint32)t;
            u32x4 A0, A1, A2, A3, B0, B1, B2, B3;
            bool d0c = false, d1c = false, d2c = false, d3c = false;
            int  spin = 0;

            asm volatile("s_waitcnt vmcnt(0)" ::: "memory");   // clean slate
            POLL_ISSUE(sp, A0, A1, A2, A3);
            for (;;) {
                // --- check generation A (issue B first: 2 gens in flight) ---
                POLL_ISSUE(sp, B0, B1, B2, B3);
                WAIT4();
                if (!d0c && __all(A0.x == tag && A0.z == tag)) {
                    *(float2*)&hw[      2 * lane] = make_float2(__uint_as_float(A0.y), __uint_as_float(A0.w));
                    d0c = true;
                }
                if (!d1c && __all(A1.x == tag && A1.z == tag)) {
                    *(float2*)&hw[132 + 2 * lane] = make_float2(__uint_as_float(A1.y), __uint_as_float(A1.w));
                    d1c = true;
                }
                if (!d2c && __all(A2.x == tag && A2.z == tag)) {
                    *(float2*)&hw[264 + 2 * lane] = make_float2(__uint_as_float(A2.y), __uint_as_float(A2.w));
                    d2c = true;
                }
                if (!d3c && __all(A3.x == tag && A3.z == tag)) {
                    *(float2*)&hw[396 + 2 * lane] = make_float2(__uint_as_float(A3.y), __uint_as_float(A3.w));
                    d3c = true;
                }
                if (d0c && d1c && d2c && d3c) {
                    asm volatile("s_waitcnt vmcnt(0)" ::: "memory");
                    break;
                }
                // --- check generation B ---
                POLL_ISSUE(sp, A0, A1, A2, A3);
                WAIT4();
                if (!d0c && __all(B0.x == tag && B0.z == tag)) {
                    *(float2*)&hw[      2 * lane] = make_float2(__uint_as_float(B0.y), __uint_as_float(B0.w));
                    d0c = true;
                }
                if (!d1c && __all(B1.x == tag && B1.z == tag)) {
                    *(float2*)&hw[132 + 2 * lane] = make_float2(__uint_as_float(B1.y), __uint_as_float(B1.w));
                    d1c = true;
                }
                if (!d2c && __all(B2.x == tag && B2.z == tag)) {
                    *(float2*)&hw[264 + 2 * lane] = make_float2(__uint_as_float(B2.y), __uint_as_float(B2.w));
                    d2c = true;
                }
                if (!d3c && __all(B3.x == tag && B3.z == tag)) {
                    *(float2*)&hw[396 + 2 * lane] = make_float2(__uint_as_float(B3.y), __uint_as_float(B3.w));
                    d3c = true;
                }
                if (d0c && d1c && d2c && d3c) {
                    asm volatile("s_waitcnt vmcnt(0)" ::: "memory");
                    break;
                }
                if (++spin > 100000) {
                    // memory-side rescue (R7-proven fresh); rare path
                    asm volatile("s_waitcnt vmcnt(0)" ::: "memory");
                    while (!(d0c && d1c && d2c && d3c)) {
                        if (!d0c) {
                            ull x0 = rescue_rmw(sp),       x1 = rescue_rmw(sp + 1);
                            if ((uint32)x0 == tag && (uint32)x1 == tag) {
                                *(float2*)&hw[      2 * lane] = make_float2(
                                    __uint_as_float((uint32)(x0 >> 32)), __uint_as_float((uint32)(x1 >> 32)));
                                d0c = true;
                            }
                        }
                        if (!d1c) {
                            ull x0 = rescue_rmw(sp + 128), x1 = rescue_rmw(sp + 129);
                            if ((uint32)x0 == tag && (uint32)x1 == tag) {
                                *(float2*)&hw[132 + 2 * lane] = make_float2(
                                    __uint_as_float((uint32)(x0 >> 32)), __uint_as_float((uint32)(x1 >> 32)));
                                d1c = true;
                            }
                        }
                        if (!d2c) {
                            ull x0 = rescue_rmw(sp + 256), x1 = rescue_rmw(sp + 257);
                            if ((uint32)x0 == tag && (uint32)x1 == tag) {
                                *(float2*)&hw[264 + 2 * lane] = make_float2(
                                    __uint_as_float((uint32)(x0 >> 32)), __uint_as_float((uint32)(x1 >> 32)));
                                d2c = true;
                            }
                        }
                        if (!d3c) {
                            ull x0 = rescue_rmw(sp + 384), x1 = rescue_rmw(sp + 385);
                            if ((uint32)x0 == tag && (uint32)x1 == tag) {
                                *(float2*)&hw[396 + 2 * lane] = make_float2(
                                    __uint_as_float((uint32)(x0 >> 32)), __uint_as_float((uint32)(x1 >> 32)));
                                d3c = true;
                            }
                        }
                    }
                    break;
                }
            }
        } else if (t == 0) {
            *(float2*)&hw[      2 * lane] = make_float2(0.f, 0.f);
            *(float2*)&hw[132 + 2 * lane] = make_float2(0.f, 0.f);
            *(float2*)&hw[264 + 2 * lane] = make_float2(0.f, 0.f);
            *(float2*)&hw[396 + 2 * lane] = make_float2(0.f, 0.f);
        }

        if (t < T_STEPS) {
            // ---- 2. mat-vec: row r, cols [cb*128, +128) ----
            float part = (cb == 0) ? gxv : 0.f;
            {
                const float4* hp4 = (const float4*)&hw[cb * 132];
                float ax = 0.f, ay = 0.f, az = 0.f, aw2 = 0.f;
                #pragma unroll
                for (int k = 0; k < 32; ++k) {
                    float4 hv = hp4[k];
                    float w0, w1, w2, w3;
                    asm volatile("v_accvgpr_read_b32 %0, %1" : "=v"(w0) : "a"(wa[4 * k + 0]));
                    asm volatile("v_accvgpr_read_b32 %0, %1" : "=v"(w1) : "a"(wa[4 * k + 1]));
                    asm volatile("v_accvgpr_read_b32 %0, %1" : "=v"(w2) : "a"(wa[4 * k + 2]));
                    asm volatile("v_accvgpr_read_b32 %0, %1" : "=v"(w3) : "a"(wa[4 * k + 3]));
                    ax  = fmaf(w0, hv.x, ax);
                    ay  = fmaf(w1, hv.y, ay);
                    az  = fmaf(w2, hv.z, az);
                    aw2 = fmaf(w3, hv.w, aw2);
                }
                part += (ax + ay) + (az + aw2);
            }
            part += __shfl_xor(part, 1);
            part += __shfl_xor(part, 2);

            // ---- 3. gates + cell update + per-lane publish (single-trip release:
            //      the fused tag IS the flag; plain write-through store to local L2) ----
            float act = (gt == 2) ? ftanh(part) : fsig(part);
            float i_v = __shfl(act, 4 * jj);
            float f_v = __shfl(act, 16 + 4 * jj);
            float g_v = __shfl(act, 32 + 4 * jj);
            float o_v = __shfl(act, 48 + 4 * jj);

            if (r < 4 && cb == 0) {      // lanes 0,4,8,12 own rows j=0..3
                c_reg = f_v * c_reg + i_v * g_v;
                float hn = o_v * ftanh(c_reg);
                ull pk = ((ull)__float_as_uint(hn) << 32) | (ull)(uint32)(t + 1);
                __hip_atomic_store(
                    &hb[(size_t)((uint32)t & (D_SLOTS - 1)) * 512 + (w << 4) + (wv << 2) + r],
                    pk, __ATOMIC_RELAXED, __HIP_MEMORY_SCOPE_WORKGROUP);
            }
        }

        // ---- 4. projection of h_{t-1} (waves 1-3, 2 dots each; after publish) ----
        if (t > 0 && wv >= 1 && ((t - 1) & 31) == w) {
            float a0 = 0.f, a1 = 0.f;
            #pragma unroll
            for (int m = 0; m < 8; ++m) {
                int c = lane + (m << 6);
                float hv = hw[((c >> 7) * 132) + (c & 127)];
                a0 = fmaf(hv, pj_lds[d0 * 512 + c],       a0);
                a1 = fmaf(hv, pj_lds[(d0 + 1) * 512 + c], a1);
            }
            a0 = wred64(a0); a1 = wred64(a1);
            if (lane == 0) {
                size_t ob = (size_t)(t - 1) * 12;
                out[ob + col0] = a0 + pb0;
                out[ob + col1] = a1 + pb1;
            }
        }
        sav = sav_n;
    }

    // keep ballast AGPRs live (branch never taken; compiler can't prove it)
    if (lstm < -1) {
        float s = 0.f;
        #pragma unroll
        for (int k = 0; k < 16; ++k) {
            float tv;
            asm volatile("v_accvgpr_read_b32 %0, %1" : "=v"(tv) : "a"(ball[k]));
            s += tv;
        }
        ((float*)claim)[31] = s;
    }
}

extern "C" void kernel_launch(void* const* d_in, const int* in_sizes, int n_in,
                              void* d_out, int out_size, void* d_ws, size_t ws_size,
                              hipStream_t stream)
{
    const float* sa    = (const float*)d_in[0];
    const float* W_ih1 = (const float*)d_in[1];
    const float* W_hh1 = (const float*)d_in[2];
    const float* b_ih1 = (const float*)d_in[3];
    const float* b_hh1 = (const float*)d_in[4];
    const float* W_ih2 = (const float*)d_in[5];
    const float* W_hh2 = (const float*)d_in[6];
    const float* b_ih2 = (const float*)d_in[7];
    const float* b_hh2 = (const float*)d_in[8];
    const float* W_xyz = (const float*)d_in[9];
    const float* b_xyz = (const float*)d_in[10];
    const float* W_zeta= (const float*)d_in[11];
    const float* b_zeta= (const float*)d_in[12];
    const float* W_uvw = (const float*)d_in[13];
    const float* b_uvw = (const float*)d_in[14];
    const float* W_pqr = (const float*)d_in[15];
    const float* b_pqr = (const float*)d_in[16];

    float*  out   = (float*)d_out;
    ull*    hrot  = (ull*)d_ws;
    uint32* claim = (uint32*)((char*)d_ws + 65536);

    // zero hrot tags + claim area every call (graph-replayed)
    hipMemsetAsync(d_ws, 0, 65536 + 128, stream);

    lstm_persistent<<<NLAUNCH, THREADS, 0, stream>>>(
        sa, W_ih1, W_hh1, b_ih1, b_hh1, W_ih2, W_hh2, b_ih2, b_hh2,
        W_xyz, b_xyz, W_zeta, b_zeta, W_uvw, b_uvw, W_pqr, b_pqr,
        out, hrot, claim);
}